// Round 7
// baseline (32136.380 us; speedup 1.0000x reference)
//
#include <hip/hip_runtime.h>
#include <hip/hip_bf16.h>
#include <hip/hip_fp16.h>

#define SEQ   4096
#define IDIM  2048
#define HDIM  2048
#define G4    8192
#define NBLK  128    // r17: 128 persistent blocks (was 256) -- smaller all-to-all fan
#define TPB   512    // 8 waves/block; per-wave structure identical to r13
#define NUNIT 8      // message units per block (one per wave; 2 cols each)
#define NREP  8      // message replicas: rb=b&7 (b%8 XCD round-robin)

typedef __attribute__((ext_vector_type(8))) short short8;   // 8 x bf16 (4 VGPRs)
typedef __attribute__((ext_vector_type(4))) float f32x4;    // MFMA accumulator

// ---------------- numerics (v_exp2 / v_rcp based, ~1e-6 rel err) ----------------
__device__ __forceinline__ float fast_sig(float x) {
    float e = __builtin_amdgcn_exp2f(-1.4426950408889634f * x);   // exp(-x)
    return __builtin_amdgcn_rcpf(1.0f + e);
}
__device__ __forceinline__ float fast_tanh(float x) {
    float e = __builtin_amdgcn_exp2f(2.8853900817779268f * x);    // exp(2x)
    return 1.0f - 2.0f * __builtin_amdgcn_rcpf(e + 1.0f);
}
__device__ __forceinline__ unsigned short f2h(float f) {
    __half h = __float2half_rn(f);
    union { __half h; unsigned short s; } c; c.h = h; return c.s;
}
__device__ __forceinline__ float h2f(unsigned short u) {
    union { unsigned short s; __half h; } c; c.s = u; return __half2float(c.h);
}

// ---------------- phase 1: xg = x @ Wih^T + bias, bf16 MFMA ---------------------
#define GM 128
#define GN 128
#define GK 32
#define APAD 40   // row pad: 80 B rows keep 16B alignment; 2-way LDS conflict (free)

__global__ __launch_bounds__(256, 2)
void xg_gemm(const float* __restrict__ x, const float* __restrict__ Wih,
             const float* __restrict__ bih, const float* __restrict__ bhh,
             __hip_bfloat16* __restrict__ xg)
{
    __shared__ __hip_bfloat16 As[GM][APAD];   // 10.25 KB
    __shared__ __hip_bfloat16 Bs[GN][APAD];

    const int t  = threadIdx.x;
    const int g0 = blockIdx.x * GN;           // 64 tiles over G4
    const int s0 = blockIdx.y * GM;           // 32 tiles over SEQ
    const int w  = t >> 6, L = t & 63;
    const int quad = L >> 4, lane16 = L & 15;
    const int wm = w >> 1, wn = w & 1;        // wave grid 2x2, each 64x64

    f32x4 acc[4][4];
#pragma unroll
    for (int mt = 0; mt < 4; ++mt)
#pragma unroll
        for (int nt = 0; nt < 4; ++nt) acc[mt][nt] = (f32x4){0.f, 0.f, 0.f, 0.f};

    const int srow = t >> 1, shalf = t & 1;   // staging: 128 rows x 2 halves of 16
    const float* xp = x   + (size_t)(s0 + srow) * IDIM + 16 * shalf;
    const float* wp = Wih + (size_t)(g0 + srow) * IDIM + 16 * shalf;

    for (int k0 = 0; k0 < IDIM; k0 += GK) {
        float4 a0 = *(const float4*)(xp + k0);
        float4 a1 = *(const float4*)(xp + k0 + 4);
        float4 a2 = *(const float4*)(xp + k0 + 8);
        float4 a3 = *(const float4*)(xp + k0 + 12);
        float4 b0 = *(const float4*)(wp + k0);
        float4 b1 = *(const float4*)(wp + k0 + 4);
        float4 b2 = *(const float4*)(wp + k0 + 8);
        float4 b3 = *(const float4*)(wp + k0 + 12);
        __syncthreads();
        {
            union { __hip_bfloat16 h[8]; uint4 u; } pk;
            pk.h[0]=__float2bfloat16(a0.x); pk.h[1]=__float2bfloat16(a0.y);
            pk.h[2]=__float2bfloat16(a0.z); pk.h[3]=__float2bfloat16(a0.w);
            pk.h[4]=__float2bfloat16(a1.x); pk.h[5]=__float2bfloat16(a1.y);
            pk.h[6]=__float2bfloat16(a1.z); pk.h[7]=__float2bfloat16(a1.w);
            *(uint4*)&As[srow][16 * shalf] = pk.u;
            pk.h[0]=__float2bfloat16(a2.x); pk.h[1]=__float2bfloat16(a2.y);
            pk.h[2]=__float2bfloat16(a2.z); pk.h[3]=__float2bfloat16(a2.w);
            pk.h[4]=__float2bfloat16(a3.x); pk.h[5]=__float2bfloat16(a3.y);
            pk.h[6]=__float2bfloat16(a3.z); pk.h[7]=__float2bfloat16(a3.w);
            *(uint4*)&As[srow][16 * shalf + 8] = pk.u;
            pk.h[0]=__float2bfloat16(b0.x); pk.h[1]=__float2bfloat16(b0.y);
            pk.h[2]=__float2bfloat16(b0.z); pk.h[3]=__float2bfloat16(b0.w);
            pk.h[4]=__float2bfloat16(b1.x); pk.h[5]=__float2bfloat16(b1.y);
            pk.h[6]=__float2bfloat16(b1.z); pk.h[7]=__float2bfloat16(b1.w);
            *(uint4*)&Bs[srow][16 * shalf] = pk.u;
            pk.h[0]=__float2bfloat16(b2.x); pk.h[1]=__float2bfloat16(b2.y);
            pk.h[2]=__float2bfloat16(b2.z); pk.h[3]=__float2bfloat16(b2.w);
            pk.h[4]=__float2bfloat16(b3.x); pk.h[5]=__float2bfloat16(b3.y);
            pk.h[6]=__float2bfloat16(b3.z); pk.h[7]=__float2bfloat16(b3.w);
            *(uint4*)&Bs[srow][16 * shalf + 8] = pk.u;
        }
        __syncthreads();

        short8 af[4], bf[4];
#pragma unroll
        for (int mt = 0; mt < 4; ++mt)
            af[mt] = *(const short8*)&As[wm * 64 + mt * 16 + lane16][quad * 8];
#pragma unroll
        for (int nt = 0; nt < 4; ++nt)
            bf[nt] = *(const short8*)&Bs[wn * 64 + nt * 16 + lane16][quad * 8];
#pragma unroll
        for (int mt = 0; mt < 4; ++mt)
#pragma unroll
            for (int nt = 0; nt < 4; ++nt)
                acc[mt][nt] = __builtin_amdgcn_mfma_f32_16x16x32_bf16(
                                  af[mt], bf[nt], acc[mt][nt], 0, 0, 0);
    }

#pragma unroll
    for (int nt = 0; nt < 4; ++nt) {
        const int g = g0 + wn * 64 + nt * 16 + lane16;
        const float bias = bih[g] + bhh[g];
#pragma unroll
        for (int mt = 0; mt < 4; ++mt) {
#pragma unroll
            for (int r = 0; r < 4; ++r) {
                const int so = s0 + wm * 64 + mt * 16 + quad * 4 + r;
                xg[(size_t)so * G4 + g] = __float2bfloat16(acc[mt][nt][r] + bias);
            }
        }
    }
}

// ---------------- phase 2: persistent LSTM recurrence --------------------------
// Round-17: HALVE THE ALL-TO-ALL FAN. r16 (exchange->store) was byte-identical
// neutral, so publish-RMW drain is NOT the bottleneck; with VALUBusy 24.5%
// (~1810cy of the 7390cy step), ~75% of step time is agent-scope visibility
// latency + max-over-N-blocks jitter (each step completes when the SLOWEST of
// N producers is seen by everyone -- extreme order statistic of N).
// Restructure: 128 blocks x 512 threads (8 waves). Per-wave shape IDENTICAL
// to the proven r13 structure: wave W owns cols {16b+2W, 16b+2W+1} x 4 gates
// (8 rows, 256 weight floats/thread = 64 VGPR), 8 hv float4 reads/thread
// (one per chunk, chunks now 256 floats, 8 of them), fold v2, in-wave gates,
// per-wave publish unit {tag:16,h0:16,h1:16}. What changes: N=128 (jitter),
// consumer thread polls 2 lines (was 4; shorter discovery chain), 16
// readers/line (was 32), 8 finer-grained chunk flags (earlier partial
// compute). Half the CUs idle -- irrelevant, we are latency-bound (HBM 1.5%,
// MFMA 0%). VGPR ~160 at 2 waves/SIMD fits (<=256).
// Transport/safety unchanged: parity double-buffer; publish(s+1) data-depends
// on full dot(s) which acquire-waits all 8 flags >= s; tag s from producer P
// implies all P's waves staged s-1 (finished reading parity-(s-1) units and
// hsh[(s-2)&1]).
__global__ __launch_bounds__(512, 1)
void lstm_rec(const float* __restrict__ Whh,
              const __hip_bfloat16* __restrict__ xg,
              float* __restrict__ hout,                 // [HDIM] final h (fp32)
              unsigned long long* __restrict__ msg)     // [2][NREP][NUNIT][NBLK], zeroed
{
    __shared__ float hsh[2][HDIM];   // 16 KB, parity double-buffer
    __shared__ int   flag[8];        // chunk-ready step markers (1 per wave)

    const int t  = threadIdx.x;      // 0..511
    const int b  = blockIdx.x;       // 0..127
    const int W  = t >> 6;           // wave 0..7
    const int L  = t & 63;
    const int hi = L & 1;            // which of the wave's 2 h-indices this lane tracks
    const int rb = b & (NREP - 1);   // replica this block polls

    // 8 rows: r=0..7 <-> gate g=r>>1, hi=r&1; global row (r>>1)*HDIM + 16b+2W+(r&1).
    // Chunk c = 256 floats; lane L reads float4 at 4L+256c. Visitation c = W^i.
    float4 wv[8][8];
#pragma unroll
    for (int r = 0; r < 8; ++r) {
        const float* rp = Whh + (size_t)((r >> 1) * HDIM + 16 * b + 2 * W + (r & 1)) * HDIM + 4 * L;
#pragma unroll
        for (int i = 0; i < 8; ++i) {
            const int c = W ^ i;
            wv[r][i] = *(const float4*)(rp + 256 * c);
        }
    }

    if (t < 8) flag[t] = -1;
    float creg = 0.0f;               // cell state for h(16b+2W+hi), per lane
    // xg pre-activations for s=0: xq[G] = xg[0][G*HDIM + 16b+2W+hi]
    float xq0, xq1, xq2, xq3;
    {
        const size_t xb = (size_t)(16 * b + 2 * W + hi);
        xq0 = __bfloat162float(xg[xb]);
        xq1 = __bfloat162float(xg[xb + HDIM]);
        xq2 = __bfloat162float(xg[xb + 2 * HDIM]);
        xq3 = __bfloat162float(xg[xb + 3 * HDIM]);
    }
    __syncthreads();                 // flag init visible

    for (int s = 0; s < SEQ; ++s) {
        const int pb = s & 1;

        // ---- stage cols [4t,4t+4) of h_s into hsh[pb] ----
        // producer p = t>>2; its units u0=2*(t&3) (cols 4t,4t+1), u0+1 (4t+2,4t+3)
        float f0,f1,f2,f3;
        if (s == 0) {
            f0=f1=f2=f3 = 0.0f;
        } else {
            const int p  = t >> 2;
            const int u0 = 2 * (t & 3);
            const unsigned long long* q0 = &msg[(size_t)((pb * NREP + rb) * NUNIT + u0) * NBLK + p];
            const unsigned long long* q1 = q0 + NBLK;   // unit u0+1
            const unsigned tgt = (unsigned)s;
            unsigned long long v0, v1;
            do {
                v0 = __hip_atomic_load(q0, __ATOMIC_RELAXED, __HIP_MEMORY_SCOPE_AGENT);
                v1 = __hip_atomic_load(q1, __ATOMIC_RELAXED, __HIP_MEMORY_SCOPE_AGENT);
            } while (min((unsigned)(v0 & 0xFFFFu), (unsigned)(v1 & 0xFFFFu)) < tgt);
            f0 = h2f((unsigned short)(v0 >> 16));
            f1 = h2f((unsigned short)(v0 >> 32));
            f2 = h2f((unsigned short)(v1 >> 16));
            f3 = h2f((unsigned short)(v1 >> 32));
        }
        float4 hv0 = { f0, f1, f2, f3 };
        *(float4*)&hsh[pb][4 * t] = hv0;
        if (L == 0)
            __hip_atomic_store(&flag[W], s, __ATOMIC_RELEASE, __HIP_MEMORY_SCOPE_WORKGROUP);

        // ---- dot: XOR visitation over 8 chunks, own chunk first ----
        float a0=0.f,a1=0.f,a2=0.f,a3=0.f,a4=0.f,a5=0.f,a6=0.f,a7=0.f;
#pragma unroll
        for (int i = 0; i < 8; ++i) {
            const int c = W ^ i;
            if (i != 0) {
                while (__hip_atomic_load(&flag[c], __ATOMIC_ACQUIRE,
                                         __HIP_MEMORY_SCOPE_WORKGROUP) < s) {}
            }
            float4 hv = *(const float4*)&hsh[pb][4 * L + 256 * c];
            a0 += wv[0][i].x*hv.x; a0 += wv[0][i].y*hv.y; a0 += wv[0][i].z*hv.z; a0 += wv[0][i].w*hv.w;
            a1 += wv[1][i].x*hv.x; a1 += wv[1][i].y*hv.y; a1 += wv[1][i].z*hv.z; a1 += wv[1][i].w*hv.w;
            a2 += wv[2][i].x*hv.x; a2 += wv[2][i].y*hv.y; a2 += wv[2][i].z*hv.z; a2 += wv[2][i].w*hv.w;
            a3 += wv[3][i].x*hv.x; a3 += wv[3][i].y*hv.y; a3 += wv[3][i].z*hv.z; a3 += wv[3][i].w*hv.w;
            a4 += wv[4][i].x*hv.x; a4 += wv[4][i].y*hv.y; a4 += wv[4][i].z*hv.z; a4 += wv[4][i].w*hv.w;
            a5 += wv[5][i].x*hv.x; a5 += wv[5][i].y*hv.y; a5 += wv[5][i].z*hv.z; a5 += wv[5][i].w*hv.w;
            a6 += wv[6][i].x*hv.x; a6 += wv[6][i].y*hv.y; a6 += wv[6][i].z*hv.z; a6 += wv[6][i].w*hv.w;
            a7 += wv[7][i].x*hv.x; a7 += wv[7][i].y*hv.y; a7 += wv[7][i].z*hv.z; a7 += wv[7][i].w*hv.w;
        }

        // ---- fold v2: level-1 folds hi; 4 gate accs through levels 2..32 ----
        float g0v = (hi ? a1 : a0) + __shfl_xor(hi ? a0 : a1, 1, 64);
        float g1v = (hi ? a3 : a2) + __shfl_xor(hi ? a2 : a3, 1, 64);
        float g2v = (hi ? a5 : a4) + __shfl_xor(hi ? a4 : a5, 1, 64);
        float g3v = (hi ? a7 : a6) + __shfl_xor(hi ? a6 : a7, 1, 64);
#pragma unroll
        for (int m = 2; m <= 32; m <<= 1) {
            g0v += __shfl_xor(g0v, m, 64);
            g1v += __shfl_xor(g1v, m, 64);
            g2v += __shfl_xor(g2v, m, 64);
            g3v += __shfl_xor(g3v, m, 64);
        }
        float pi = g0v + xq0;
        float pf = g1v + xq1;
        float pg = g2v + xq2;
        float po = g3v + xq3;

        // ---- gates, in every lane (redundant across lanes, no LDS) ----
        float cn = fast_sig(pf) * creg + fast_sig(pi) * fast_tanh(pg);
        creg = cn;
        float h = fast_sig(po) * fast_tanh(cn);
        if (s == SEQ - 1 && L < 2) hout[16 * b + 2 * W + L] = h;

        if (s + 1 < SEQ) {
            const int p2 = (s + 1) & 1;
            float hp = __shfl_xor(h, 1, 64);          // partner column's h
            float h0 = hi ? hp : h;
            float h1 = hi ? h : hp;
            if (L < NREP) {
                unsigned long long u = (unsigned long long)(unsigned short)(s + 1)
                    | ((unsigned long long)f2h(h0) << 16)
                    | ((unsigned long long)f2h(h1) << 32);
                __hip_atomic_store(
                        &msg[(size_t)((p2 * NREP + L) * NUNIT + W) * NBLK + b], u,
                        __ATOMIC_RELAXED, __HIP_MEMORY_SCOPE_AGENT);
            }
            // prefetch xg for s+1 (hidden under next iteration's poll)
            const size_t xb = (size_t)(s + 1) * G4 + 16 * b + 2 * W + hi;
            xq0 = __bfloat162float(xg[xb]);
            xq1 = __bfloat162float(xg[xb + HDIM]);
            xq2 = __bfloat162float(xg[xb + 2 * HDIM]);
            xq3 = __bfloat162float(xg[xb + 3 * HDIM]);
        }
    }
}

// ---------------- phase 3: out[o] = h . Wfc[o,:] + bfc[o] ----------------------
__global__ __launch_bounds__(64)
void fc_kernel(const float* __restrict__ h, const float* __restrict__ Wfc,
               const float* __restrict__ bfc, float* __restrict__ out)
{
    const int o = blockIdx.x;
    const int L = threadIdx.x;
    const float* wr = Wfc + (size_t)o * HDIM;
    float s = 0.0f;
#pragma unroll
    for (int jj = 0; jj < 8; ++jj) {
        float4 wvv = *(const float4*)(wr + 4 * (L + 64 * jj));
        float4 hv  = *(const float4*)(h  + 4 * (L + 64 * jj));
        s += wvv.x * hv.x + wvv.y * hv.y + wvv.z * hv.z + wvv.w * hv.w;
    }
#pragma unroll
    for (int mask = 1; mask <= 32; mask <<= 1) s += __shfl_xor(s, mask, 64);
    if (L == 0) out[o] = s + bfc[o];
}

// ---------------- launcher -----------------------------------------------------
extern "C" void kernel_launch(void* const* d_in, const int* in_sizes, int n_in,
                              void* d_out, int out_size, void* d_ws, size_t ws_size,
                              hipStream_t stream)
{
    (void)in_sizes; (void)n_in; (void)out_size; (void)ws_size;
    const float* x   = (const float*)d_in[0];
    const float* Wih = (const float*)d_in[1];
    const float* Whh = (const float*)d_in[2];
    const float* bih = (const float*)d_in[3];
    const float* bhh = (const float*)d_in[4];
    const float* Wfc = (const float*)d_in[5];
    const float* bfc = (const float*)d_in[6];
    float* out = (float*)d_out;

    // ws layout: xg bf16 [SEQ][G4] (64 MiB) | hout fp32 [HDIM] | msg u64 [2][NREP][NUNIT][NBLK]
    __hip_bfloat16* xg       = (__hip_bfloat16*)d_ws;
    float* hout              = (float*)((char*)d_ws + (size_t)SEQ * G4 * sizeof(__hip_bfloat16));
    unsigned long long* msg  = (unsigned long long*)(hout + HDIM);

    // ws is poisoned 0xAA before every launch -> tags would read as fresh; MUST zero.
    (void)hipMemsetAsync(msg, 0, (size_t)2 * NREP * NUNIT * NBLK * sizeof(unsigned long long), stream);

    dim3 g1(G4 / GN, SEQ / GM);  // (64, 32)
    hipLaunchKernelGGL(xg_gemm, g1, dim3(256), 0, stream, x, Wih, bih, bhh, xg);

    // lstm_rec needs all 128 blocks co-resident. Prefer the cooperative-launch
    // guarantee; if the API refuses, fall back to a plain launch: grid==128
    // with 1 block/CU on an idle 256-CU device is co-resident by construction.
    float* hout_arg = hout;
    unsigned long long* msg_arg = msg;
    void* args[] = { (void*)&Whh, (void*)&xg, (void*)&hout_arg, (void*)&msg_arg };
    hipError_t ce = hipLaunchCooperativeKernel((const void*)lstm_rec, dim3(NBLK), dim3(TPB),
                                               args, 0, stream);
    if (ce != hipSuccess) {
        hipLaunchKernelGGL(lstm_rec, dim3(NBLK), dim3(TPB), 0, stream, Whh, xg, hout, msg);
    }

    hipLaunchKernelGGL(fc_kernel, dim3(2048), dim3(64), 0, stream, hout, Wfc, bfc, out);
}

// Round 8
// 12977.094 us; speedup vs baseline: 2.4764x; 2.4764x over previous
//
#include <hip/hip_runtime.h>
#include <hip/hip_bf16.h>
#include <hip/hip_fp16.h>

#define SEQ   4096
#define IDIM  2048
#define HDIM  2048
#define G4    8192
#define NBLK  256
#define NREP  8      // message replicas: rb=b&7 aligns replica r with XCD r (b%8 dispatch)

typedef __attribute__((ext_vector_type(8))) short short8;   // 8 x bf16 (4 VGPRs)
typedef __attribute__((ext_vector_type(4))) float f32x4;    // MFMA accumulator

// ---------------- numerics (v_exp2 / v_rcp based, ~1e-6 rel err) ----------------
__device__ __forceinline__ float fast_sig(float x) {
    float e = __builtin_amdgcn_exp2f(-1.4426950408889634f * x);   // exp(-x)
    return __builtin_amdgcn_rcpf(1.0f + e);
}
__device__ __forceinline__ float fast_tanh(float x) {
    float e = __builtin_amdgcn_exp2f(2.8853900817779268f * x);    // exp(2x)
    return 1.0f - 2.0f * __builtin_amdgcn_rcpf(e + 1.0f);
}
__device__ __forceinline__ unsigned short f2h(float f) {
    __half h = __float2half_rn(f);
    union { __half h; unsigned short s; } c; c.h = h; return c.s;
}
__device__ __forceinline__ float h2f(unsigned short u) {
    union { unsigned short s; __half h; } c; c.s = u; return __half2float(c.h);
}

// ---------------- phase 1: xg = x @ Wih^T + bias, bf16 MFMA ---------------------
#define GM 128
#define GN 128
#define GK 32
#define APAD 40   // row pad: 80 B rows keep 16B alignment; 2-way LDS conflict (free)

__global__ __launch_bounds__(256, 2)
void xg_gemm(const float* __restrict__ x, const float* __restrict__ Wih,
             const float* __restrict__ bih, const float* __restrict__ bhh,
             __hip_bfloat16* __restrict__ xg)
{
    __shared__ __hip_bfloat16 As[GM][APAD];   // 10.25 KB
    __shared__ __hip_bfloat16 Bs[GN][APAD];

    const int t  = threadIdx.x;
    const int g0 = blockIdx.x * GN;           // 64 tiles over G4
    const int s0 = blockIdx.y * GM;           // 32 tiles over SEQ
    const int w  = t >> 6, L = t & 63;
    const int quad = L >> 4, lane16 = L & 15;
    const int wm = w >> 1, wn = w & 1;        // wave grid 2x2, each 64x64

    f32x4 acc[4][4];
#pragma unroll
    for (int mt = 0; mt < 4; ++mt)
#pragma unroll
        for (int nt = 0; nt < 4; ++nt) acc[mt][nt] = (f32x4){0.f, 0.f, 0.f, 0.f};

    const int srow = t >> 1, shalf = t & 1;   // staging: 128 rows x 2 halves of 16
    const float* xp = x   + (size_t)(s0 + srow) * IDIM + 16 * shalf;
    const float* wp = Wih + (size_t)(g0 + srow) * IDIM + 16 * shalf;

    for (int k0 = 0; k0 < IDIM; k0 += GK) {
        float4 a0 = *(const float4*)(xp + k0);
        float4 a1 = *(const float4*)(xp + k0 + 4);
        float4 a2 = *(const float4*)(xp + k0 + 8);
        float4 a3 = *(const float4*)(xp + k0 + 12);
        float4 b0 = *(const float4*)(wp + k0);
        float4 b1 = *(const float4*)(wp + k0 + 4);
        float4 b2 = *(const float4*)(wp + k0 + 8);
        float4 b3 = *(const float4*)(wp + k0 + 12);
        __syncthreads();
        {
            union { __hip_bfloat16 h[8]; uint4 u; } pk;
            pk.h[0]=__float2bfloat16(a0.x); pk.h[1]=__float2bfloat16(a0.y);
            pk.h[2]=__float2bfloat16(a0.z); pk.h[3]=__float2bfloat16(a0.w);
            pk.h[4]=__float2bfloat16(a1.x); pk.h[5]=__float2bfloat16(a1.y);
            pk.h[6]=__float2bfloat16(a1.z); pk.h[7]=__float2bfloat16(a1.w);
            *(uint4*)&As[srow][16 * shalf] = pk.u;
            pk.h[0]=__float2bfloat16(a2.x); pk.h[1]=__float2bfloat16(a2.y);
            pk.h[2]=__float2bfloat16(a2.z); pk.h[3]=__float2bfloat16(a2.w);
            pk.h[4]=__float2bfloat16(a3.x); pk.h[5]=__float2bfloat16(a3.y);
            pk.h[6]=__float2bfloat16(a3.z); pk.h[7]=__float2bfloat16(a3.w);
            *(uint4*)&As[srow][16 * shalf + 8] = pk.u;
            pk.h[0]=__float2bfloat16(b0.x); pk.h[1]=__float2bfloat16(b0.y);
            pk.h[2]=__float2bfloat16(b0.z); pk.h[3]=__float2bfloat16(b0.w);
            pk.h[4]=__float2bfloat16(b1.x); pk.h[5]=__float2bfloat16(b1.y);
            pk.h[6]=__float2bfloat16(b1.z); pk.h[7]=__float2bfloat16(b1.w);
            *(uint4*)&Bs[srow][16 * shalf] = pk.u;
            pk.h[0]=__float2bfloat16(b2.x); pk.h[1]=__float2bfloat16(b2.y);
            pk.h[2]=__float2bfloat16(b2.z); pk.h[3]=__float2bfloat16(b2.w);
            pk.h[4]=__float2bfloat16(b3.x); pk.h[5]=__float2bfloat16(b3.y);
            pk.h[6]=__float2bfloat16(b3.z); pk.h[7]=__float2bfloat16(b3.w);
            *(uint4*)&Bs[srow][16 * shalf + 8] = pk.u;
        }
        __syncthreads();

        short8 af[4], bf[4];
#pragma unroll
        for (int mt = 0; mt < 4; ++mt)
            af[mt] = *(const short8*)&As[wm * 64 + mt * 16 + lane16][quad * 8];
#pragma unroll
        for (int nt = 0; nt < 4; ++nt)
            bf[nt] = *(const short8*)&Bs[wn * 64 + nt * 16 + lane16][quad * 8];
#pragma unroll
        for (int mt = 0; mt < 4; ++mt)
#pragma unroll
            for (int nt = 0; nt < 4; ++nt)
                acc[mt][nt] = __builtin_amdgcn_mfma_f32_16x16x32_bf16(
                                  af[mt], bf[nt], acc[mt][nt], 0, 0, 0);
    }

#pragma unroll
    for (int nt = 0; nt < 4; ++nt) {
        const int g = g0 + wn * 64 + nt * 16 + lane16;
        const float bias = bih[g] + bhh[g];
#pragma unroll
        for (int mt = 0; mt < 4; ++mt) {
#pragma unroll
            for (int r = 0; r < 4; ++r) {
                const int so = s0 + wm * 64 + mt * 16 + quad * 4 + r;
                xg[(size_t)so * G4 + g] = __float2bfloat16(acc[mt][nt][r] + bias);
            }
        }
    }
}

// ---------------- phase 2: persistent LSTM recurrence --------------------------
// Wave-owns-h-columns structure (r13): 256 blocks x 256 threads, 1/CU. Block b
// owns h[8b..8b+8); wave w owns h indices {8b+2w, 8b+2w+1} across ALL 4 gates
// (8 weight rows/wave). Lane L holds k-slices; each hsh float4 read reused 8x.
// Fully in-wave tail (no barrier B / gsum / hloc). Transport: 4 units/block
// ({tag:16,h0:16,h1:16} per wave) x NREP replicas, relaxed atomic-store
// publish, parity double-buffer; consumer thread t polls all 4 units of
// producer t.
//
// Round-18: PURE REVERT to r16 (the best verified kernel) after r17's 2.5x
// regression. r17 ledger entry: 128 blocks x 512 threads halved the fan but
// WRITE_SIZE exploded 1.05->3.83 GB with IDENTICAL per-step store counts and
// dirty-line counts -> the new shape (16 reader-blocks/line, finer chunk
// flags, longer line residence) drove cross-XCD line ping-pong with HBM
// writeback on每 ownership transfer; VALUBusy 24.5->8.1% (waves 3x longer
// blocked). Fan-size/jitter theory FALSIFIED. Transport theories now dead:
// poll depth (r11, hurt), RMW drain (r16, neutral), fan size (r17, big
// regression). The 256-block/4-unit/8-replica operating point is a tuned
// equilibrium; remaining candidates are sub-5% micro (permlane fold,
// pk_fma), else structural floor ~3us/step = publish->L3->discover round
// trip + serial dot/fold tail.
// Overwrite safety (r13 argument): publish(s+1) data-depends on full dot(s)
// which acquire-waits all 4 flags >= s; tag s from producer P implies all
// P's waves staged s-1. Two-parity double-buffer closes both hazards.
__global__ __launch_bounds__(256, 1)
void lstm_rec(const float* __restrict__ Whh,
              const __hip_bfloat16* __restrict__ xg,
              float* __restrict__ hout,                 // [HDIM] final h (fp32)
              unsigned long long* __restrict__ msg)     // [2][NREP][4][NBLK], zeroed
{
    __shared__ float hsh[2][HDIM];   // 16 KB, parity double-buffer
    __shared__ int   flag[4];        // chunk-ready step markers

    const int t  = threadIdx.x;
    const int b  = blockIdx.x;
    const int w  = t >> 6;
    const int L  = t & 63;
    const int hi = L & 1;            // which of the wave's 2 h-indices this lane tracks
    const int rb = b & (NREP - 1);   // replica this block polls

    // 8 rows: r=0..7 <-> gate g=r>>1, hi=r&1; global row (r>>1)*HDIM + 8b+2w+(r&1).
    // Lane L holds k = 4L + 512c + 256u for c = w^i (visitation order), u=0..1.
    // wv[r][2i+u] <-> chunk w^i, half u: register index compile-time.
    float4 wv[8][8];
#pragma unroll
    for (int r = 0; r < 8; ++r) {
        const float* rp = Whh + (size_t)((r >> 1) * HDIM + 8 * b + 2 * w + (r & 1)) * HDIM + 4 * L;
#pragma unroll
        for (int i = 0; i < 4; ++i) {
            const int c = w ^ i;
#pragma unroll
            for (int u = 0; u < 2; ++u)
                wv[r][2 * i + u] = *(const float4*)(rp + 512 * c + 256 * u);
        }
    }

    if (t < 4) flag[t] = -1;
    float creg = 0.0f;               // cell state for h(8b+2w+hi), per lane
    // xg pre-activations for s=0: xq[G] = xg[0][G*HDIM + 8b+2w+hi]
    float xq0, xq1, xq2, xq3;
    {
        const size_t xb = (size_t)(8 * b + 2 * w + hi);
        xq0 = __bfloat162float(xg[xb]);
        xq1 = __bfloat162float(xg[xb + HDIM]);
        xq2 = __bfloat162float(xg[xb + 2 * HDIM]);
        xq3 = __bfloat162float(xg[xb + 3 * HDIM]);
    }
    __syncthreads();                 // flag init visible

    for (int s = 0; s < SEQ; ++s) {
        const int pb = s & 1;

        // ---- stage chunk w of h_s into hsh[pb] (thread t <-> producer t) ----
        float f0,f1,f2,f3,f4,f5,f6,f7;
        if (s == 0) {
            f0=f1=f2=f3=f4=f5=f6=f7 = 0.0f;
        } else {
            const unsigned long long* p0 = &msg[(size_t)((pb * NREP + rb) * 4 + 0) * NBLK + t];
            const unsigned long long* p1 = &msg[(size_t)((pb * NREP + rb) * 4 + 1) * NBLK + t];
            const unsigned long long* p2 = &msg[(size_t)((pb * NREP + rb) * 4 + 2) * NBLK + t];
            const unsigned long long* p3 = &msg[(size_t)((pb * NREP + rb) * 4 + 3) * NBLK + t];
            const unsigned tgt = (unsigned)s;
            unsigned long long v0, v1, v2, v3;
            do {
                v0 = __hip_atomic_load(p0, __ATOMIC_RELAXED, __HIP_MEMORY_SCOPE_AGENT);
                v1 = __hip_atomic_load(p1, __ATOMIC_RELAXED, __HIP_MEMORY_SCOPE_AGENT);
                v2 = __hip_atomic_load(p2, __ATOMIC_RELAXED, __HIP_MEMORY_SCOPE_AGENT);
                v3 = __hip_atomic_load(p3, __ATOMIC_RELAXED, __HIP_MEMORY_SCOPE_AGENT);
            } while (min(min((unsigned)(v0 & 0xFFFFu), (unsigned)(v1 & 0xFFFFu)),
                         min((unsigned)(v2 & 0xFFFFu), (unsigned)(v3 & 0xFFFFu))) < tgt);
            f0 = h2f((unsigned short)(v0 >> 16));
            f1 = h2f((unsigned short)(v0 >> 32));
            f2 = h2f((unsigned short)(v1 >> 16));
            f3 = h2f((unsigned short)(v1 >> 32));
            f4 = h2f((unsigned short)(v2 >> 16));
            f5 = h2f((unsigned short)(v2 >> 32));
            f6 = h2f((unsigned short)(v3 >> 16));
            f7 = h2f((unsigned short)(v3 >> 32));
        }
        float4 hv0 = { f0, f1, f2, f3 };
        float4 hv1 = { f4, f5, f6, f7 };
        *(float4*)&hsh[pb][8 * t]     = hv0;
        *(float4*)&hsh[pb][8 * t + 4] = hv1;
        if (L == 0)
            __hip_atomic_store(&flag[w], s, __ATOMIC_RELEASE, __HIP_MEMORY_SCOPE_WORKGROUP);

        // ---- dot: XOR visitation, own chunk first; 8 ds_read_b128/thread ----
        float a0=0.f,a1=0.f,a2=0.f,a3=0.f,a4=0.f,a5=0.f,a6=0.f,a7=0.f;
#pragma unroll
        for (int i = 0; i < 4; ++i) {
            const int c = w ^ i;
            if (i != 0) {
                while (__hip_atomic_load(&flag[c], __ATOMIC_ACQUIRE,
                                         __HIP_MEMORY_SCOPE_WORKGROUP) < s) {}
            }
#pragma unroll
            for (int u = 0; u < 2; ++u) {
                const int q = 2 * i + u;   // compile-time register index
                float4 hv = *(const float4*)&hsh[pb][4 * L + 512 * c + 256 * u];
                a0 += wv[0][q].x*hv.x; a0 += wv[0][q].y*hv.y; a0 += wv[0][q].z*hv.z; a0 += wv[0][q].w*hv.w;
                a1 += wv[1][q].x*hv.x; a1 += wv[1][q].y*hv.y; a1 += wv[1][q].z*hv.z; a1 += wv[1][q].w*hv.w;
                a2 += wv[2][q].x*hv.x; a2 += wv[2][q].y*hv.y; a2 += wv[2][q].z*hv.z; a2 += wv[2][q].w*hv.w;
                a3 += wv[3][q].x*hv.x; a3 += wv[3][q].y*hv.y; a3 += wv[3][q].z*hv.z; a3 += wv[3][q].w*hv.w;
                a4 += wv[4][q].x*hv.x; a4 += wv[4][q].y*hv.y; a4 += wv[4][q].z*hv.z; a4 += wv[4][q].w*hv.w;
                a5 += wv[5][q].x*hv.x; a5 += wv[5][q].y*hv.y; a5 += wv[5][q].z*hv.z; a5 += wv[5][q].w*hv.w;
                a6 += wv[6][q].x*hv.x; a6 += wv[6][q].y*hv.y; a6 += wv[6][q].z*hv.z; a6 += wv[6][q].w*hv.w;
                a7 += wv[7][q].x*hv.x; a7 += wv[7][q].y*hv.y; a7 += wv[7][q].z*hv.z; a7 += wv[7][q].w*hv.w;
            }
        }

        // ---- fold v2: level-1 folds hi; 4 gate accs through levels 2..32 ----
        // (depth 6, no gathers: every lane ends with all 4 gate totals for hi)
        float g0v = (hi ? a1 : a0) + __shfl_xor(hi ? a0 : a1, 1, 64);
        float g1v = (hi ? a3 : a2) + __shfl_xor(hi ? a2 : a3, 1, 64);
        float g2v = (hi ? a5 : a4) + __shfl_xor(hi ? a4 : a5, 1, 64);
        float g3v = (hi ? a7 : a6) + __shfl_xor(hi ? a6 : a7, 1, 64);
#pragma unroll
        for (int m = 2; m <= 32; m <<= 1) {
            g0v += __shfl_xor(g0v, m, 64);
            g1v += __shfl_xor(g1v, m, 64);
            g2v += __shfl_xor(g2v, m, 64);
            g3v += __shfl_xor(g3v, m, 64);
        }
        float pi = g0v + xq0;
        float pf = g1v + xq1;
        float pg = g2v + xq2;
        float po = g3v + xq3;

        // ---- gates, in every lane (redundant across lanes, no LDS) ----
        float cn = fast_sig(pf) * creg + fast_sig(pi) * fast_tanh(pg);
        creg = cn;
        float h = fast_sig(po) * fast_tanh(cn);
        if (s == SEQ - 1 && L < 2) hout[8 * b + 2 * w + L] = h;

        if (s + 1 < SEQ) {
            const int p = (s + 1) & 1;
            float hp = __shfl_xor(h, 1, 64);          // partner column's h
            float h0 = hi ? hp : h;
            float h1 = hi ? h : hp;
            if (L < NREP) {
                unsigned long long u = (unsigned long long)(unsigned short)(s + 1)
                    | ((unsigned long long)f2h(h0) << 16)
                    | ((unsigned long long)f2h(h1) << 32);
                // pure store, not exchange: no RMW serialization at the
                // coherence point; aligned u64 store is single-copy atomic.
                __hip_atomic_store(
                        &msg[(size_t)((p * NREP + L) * 4 + w) * NBLK + b], u,
                        __ATOMIC_RELAXED, __HIP_MEMORY_SCOPE_AGENT);
            }
            // prefetch xg for s+1 (hidden under next iteration's poll)
            const size_t xb = (size_t)(s + 1) * G4 + 8 * b + 2 * w + hi;
            xq0 = __bfloat162float(xg[xb]);
            xq1 = __bfloat162float(xg[xb + HDIM]);
            xq2 = __bfloat162float(xg[xb + 2 * HDIM]);
            xq3 = __bfloat162float(xg[xb + 3 * HDIM]);
        }
    }
}

// ---------------- phase 3: out[o] = h . Wfc[o,:] + bfc[o] ----------------------
__global__ __launch_bounds__(64)
void fc_kernel(const float* __restrict__ h, const float* __restrict__ Wfc,
               const float* __restrict__ bfc, float* __restrict__ out)
{
    const int o = blockIdx.x;
    const int L = threadIdx.x;
    const float* wr = Wfc + (size_t)o * HDIM;
    float s = 0.0f;
#pragma unroll
    for (int jj = 0; jj < 8; ++jj) {
        float4 wvv = *(const float4*)(wr + 4 * (L + 64 * jj));
        float4 hv  = *(const float4*)(h  + 4 * (L + 64 * jj));
        s += wvv.x * hv.x + wvv.y * hv.y + wvv.z * hv.z + wvv.w * hv.w;
    }
#pragma unroll
    for (int mask = 1; mask <= 32; mask <<= 1) s += __shfl_xor(s, mask, 64);
    if (L == 0) out[o] = s + bfc[o];
}

// ---------------- launcher -----------------------------------------------------
extern "C" void kernel_launch(void* const* d_in, const int* in_sizes, int n_in,
                              void* d_out, int out_size, void* d_ws, size_t ws_size,
                              hipStream_t stream)
{
    (void)in_sizes; (void)n_in; (void)out_size; (void)ws_size;
    const float* x   = (const float*)d_in[0];
    const float* Wih = (const float*)d_in[1];
    const float* Whh = (const float*)d_in[2];
    const float* bih = (const float*)d_in[3];
    const float* bhh = (const float*)d_in[4];
    const float* Wfc = (const float*)d_in[5];
    const float* bfc = (const float*)d_in[6];
    float* out = (float*)d_out;

    // ws layout: xg bf16 [SEQ][G4] (64 MiB) | hout fp32 [HDIM] | msg u64 [2][NREP][4][NBLK]
    __hip_bfloat16* xg       = (__hip_bfloat16*)d_ws;
    float* hout              = (float*)((char*)d_ws + (size_t)SEQ * G4 * sizeof(__hip_bfloat16));
    unsigned long long* msg  = (unsigned long long*)(hout + HDIM);

    // ws is poisoned 0xAA before every launch -> tags would read as fresh; MUST zero.
    (void)hipMemsetAsync(msg, 0, (size_t)2 * NREP * 4 * NBLK * sizeof(unsigned long long), stream);

    dim3 g1(G4 / GN, SEQ / GM);  // (64, 32)
    hipLaunchKernelGGL(xg_gemm, g1, dim3(256), 0, stream, x, Wih, bih, bhh, xg);

    // lstm_rec needs all 256 blocks co-resident. Prefer the cooperative-launch
    // guarantee; if the API refuses, fall back to a plain launch: grid==256
    // with 1 block/CU on an idle 256-CU device is co-resident by construction.
    float* hout_arg = hout;
    unsigned long long* msg_arg = msg;
    void* args[] = { (void*)&Whh, (void*)&xg, (void*)&hout_arg, (void*)&msg_arg };
    hipError_t ce = hipLaunchCooperativeKernel((const void*)lstm_rec, dim3(NBLK), dim3(256),
                                               args, 0, stream);
    if (ce != hipSuccess) {
        hipLaunchKernelGGL(lstm_rec, dim3(NBLK), dim3(256), 0, stream, Whh, xg, hout, msg);
    }

    hipLaunchKernelGGL(fc_kernel, dim3(2048), dim3(64), 0, stream, hout, Wfc, bfc, out);
}